// Round 12
// baseline (502.689 us; speedup 1.0000x reference)
//
#include <hip/hip_runtime.h>
#include <hip/hip_fp16.h>

#define TT 512
#define HH 128
#define MAGIC 0x13572468

typedef _Float16 half2_t __attribute__((ext_vector_type(2)));
typedef _Float16 half4_t __attribute__((ext_vector_type(4)));
typedef _Float16 half8_t __attribute__((ext_vector_type(8)));
typedef float    float4_t __attribute__((ext_vector_type(4)));

__device__ __forceinline__ half2_t h2(float v) {
    half2_t r; r[0] = (_Float16)v; r[1] = (_Float16)v; return r;
}
__device__ __forceinline__ half2_t pkrtz(float a, float b) {
    return __builtin_bit_cast(half2_t, __builtin_amdgcn_cvt_pkrtz(a, b));
}

// ---- packed-f16 polynomial activations (no transcendentals) ----
#define TC1 0.994940f
#define TC3 -0.290799f
#define TC5 0.065507f
#define TC7 -0.0062464f
#define SC1 0.2487350f
#define SC3 -0.0181749f
#define SC5 0.00102355f
#define SC7 -0.0000244141f

__device__ __forceinline__ half2_t tanh_pk(half2_t x) {
    half2_t m = __builtin_elementwise_min(__builtin_elementwise_max(x, h2(-2.0f)), h2(2.0f));
    half2_t t = m * m;
    half2_t p = h2(TC7) * t + h2(TC5);
    p = p * t + h2(TC3);
    p = p * t + h2(TC1);
    return m * p;
}
__device__ __forceinline__ half2_t sigma_pk(half2_t x) {
    half2_t m = __builtin_elementwise_min(__builtin_elementwise_max(x, h2(-4.0f)), h2(4.0f));
    half2_t t = m * m;
    half2_t p = h2(SC7) * t + h2(SC5);
    p = p * t + h2(SC3);
    p = p * t + h2(SC1);
    return m * p + h2(0.5f);
}

// LDS-only barrier: waits lgkmcnt(0), leaves global loads/stores in flight.
__device__ __forceinline__ void wg_barrier_lds() {
#if __has_builtin(__builtin_amdgcn_s_waitcnt)
    __builtin_amdgcn_s_waitcnt(0xC07F);   // lgkmcnt(0), vmcnt=max, expcnt=max
#else
    asm volatile("s_waitcnt lgkmcnt(0)" ::: "memory");
#endif
    __builtin_amdgcn_s_barrier();
}

// xp layout (f16): half index = (((dirbg*512 + t)*8 + w)*64 + lane)*16.
// Cache lines (128B) cover 4 lanes of ONE t -> lines never span chunk
// boundaries (critical for the producer/consumer coherence protocol).
__device__ __forceinline__ size_t xp_off(int dirbg, int t, int w, int lane) {
    return (((size_t)dirbg * 512 + t) * 8 + w) * 1024 + (size_t)lane * 16;
}

// consumer-side gate: tid0 acquire-spins (invalidates this CU's L1/L2 so the
// producer's flushed lines are refetched from LLC), then block-wide barrier.
__device__ __forceinline__ void gate_chunks(const int* flags, int base, int c0, int c1, int tid) {
    if (tid == 0) {
        while (__hip_atomic_load(flags + base + c0, __ATOMIC_ACQUIRE,
                                 __HIP_MEMORY_SCOPE_AGENT) != MAGIC) {}
        if (c1 >= 0 && c1 < 32)
            while (__hip_atomic_load(flags + base + c1, __ATOMIC_ACQUIRE,
                                     __HIP_MEMORY_SCOPE_AGENT) != MAGIC) {}
    }
    __syncthreads();
}

// ---- mega kernel: WGs 0..15 = recurrence consumers (dirbg); WGs 16..527 =
// xp producers (r11 staged GEMM, one (dirbg, 16-t chunk) each, priority-
// ordered so first-needed chunks have lowest blockIdx).
__global__ __attribute__((amdgpu_flat_work_group_size(512, 512), amdgpu_waves_per_eu(2, 2)))
void bilstm_mega_kernel(
    const int* __restrict__ x, const float* __restrict__ emb,
    const float* __restrict__ Wih_f, const float* __restrict__ bih_f, const float* __restrict__ bhh_f,
    const float* __restrict__ Wih_b, const float* __restrict__ bih_b, const float* __restrict__ bhh_b,
    const float* __restrict__ Whh_f, const float* __restrict__ Whh_b,
    _Float16* __restrict__ xp, int* __restrict__ flags,
    float* __restrict__ pooled)
{
    __shared__ __align__(16) char smem[1024 + 256 * 136 * 2];   // 70.7 KB, aliased

    const int tid = threadIdx.x;
    const int w = tid >> 6, lane = tid & 63, lq = lane >> 4, lm = lane & 15;

    if (blockIdx.x >= 16) {
        // ================= PRODUCER: staged xp GEMM for one chunk ==========
        const int pid  = blockIdx.x - 16;         // 0..511
        const int prio = pid >> 4;                // 0..31
        const int dirbg = pid & 15;
        const int dir = dirbg >> 3, bg = dirbg & 7;
        const int chunk = dir ? (31 - prio) : prio;
        const int tb = chunk * 16;

        const float* Wih = dir ? Wih_b : Wih_f;
        const float* bih = dir ? bih_b : bih_f;
        const float* bhh = dir ? bhh_b : bhh_f;

        int* id_sm = (int*)smem;                         // 256 ints
        _Float16* Esm = (_Float16*)(smem + 1024);        // [t*16+chain][136]

        if (tid < 256)
            id_sm[tid] = x[(size_t)(bg * 16 + (tid >> 4)) * TT + tb + (tid & 15)];

        half8_t awih[4][4];
        #pragma unroll
        for (int T = 0; T < 4; ++T) {
            #pragma unroll
            for (int kk = 0; kk < 4; ++kk) {
                const float4* s = (const float4*)(Wih + (size_t)(T * 128 + w * 16 + lm) * 128 + kk * 32 + lq * 8);
                float4 v0 = s[0], v1 = s[1];
                half8_t h;
                half2_t a = pkrtz(v0.x, v0.y), b = pkrtz(v0.z, v0.w);
                half2_t c = pkrtz(v1.x, v1.y), d = pkrtz(v1.z, v1.w);
                h[0]=a[0]; h[1]=a[1]; h[2]=b[0]; h[3]=b[1];
                h[4]=c[0]; h[5]=c[1]; h[6]=d[0]; h[7]=d[1];
                awih[T][kk] = h;
            }
        }
        float4_t biasv[4];
        #pragma unroll
        for (int T = 0; T < 4; ++T) {
            int g = T * 128 + w * 16 + lq * 4;
            float4 b1 = *(const float4*)(bih + g);
            float4 b2 = *(const float4*)(bhh + g);
            biasv[T] = (float4_t){b1.x + b2.x, b1.y + b2.y, b1.z + b2.z, b1.w + b2.w};
        }
        __syncthreads();   // id_sm ready

        {   // stage phase: 2 threads per (chain,t) row, 16 float4 each
            const int r  = tid >> 1;
            const int hf = tid & 1;
            const int chain = r >> 4, tt2 = r & 15;
            const float* src = emb + (size_t)id_sm[r] * 128 + hf * 64;
            float4 v[16];
            #pragma unroll
            for (int j = 0; j < 16; ++j) v[j] = *(const float4*)(src + 4 * j);
            _Float16* dst = &Esm[(tt2 * 16 + chain) * 136 + hf * 64];
            #pragma unroll
            for (int j = 0; j < 16; ++j) {
                half2_t a = pkrtz(v[j].x, v[j].y), b = pkrtz(v[j].z, v[j].w);
                half4_t q; q[0]=a[0]; q[1]=a[1]; q[2]=b[0]; q[3]=b[1];
                *(half4_t*)(dst + 4 * j) = q;
            }
        }
        __syncthreads();   // Esm ready

        #pragma unroll 4
        for (int i = 0; i < 16; ++i) {
            half8_t bfr[4];
            #pragma unroll
            for (int kk = 0; kk < 4; ++kk)
                bfr[kk] = *(const half8_t*)&Esm[(i * 16 + lm) * 136 + kk * 32 + lq * 8];

            float4_t acc[4];
            #pragma unroll
            for (int T = 0; T < 4; ++T) acc[T] = biasv[T];
            #pragma unroll
            for (int kk = 0; kk < 4; ++kk)
                #pragma unroll
                for (int T = 0; T < 4; ++T)
                    acc[T] = __builtin_amdgcn_mfma_f32_16x16x32_f16(awih[T][kk], bfr[kk], acc[T], 0, 0, 0);

            half8_t p0, p1;
            {
                half2_t a = pkrtz(acc[0][0], acc[0][1]), b = pkrtz(acc[0][2], acc[0][3]);
                half2_t c = pkrtz(acc[1][0], acc[1][1]), d = pkrtz(acc[1][2], acc[1][3]);
                p0[0]=a[0]; p0[1]=a[1]; p0[2]=b[0]; p0[3]=b[1];
                p0[4]=c[0]; p0[5]=c[1]; p0[6]=d[0]; p0[7]=d[1];
            }
            {
                half2_t a = pkrtz(acc[2][0], acc[2][1]), b = pkrtz(acc[2][2], acc[2][3]);
                half2_t c = pkrtz(acc[3][0], acc[3][1]), d = pkrtz(acc[3][2], acc[3][3]);
                p1[0]=a[0]; p1[1]=a[1]; p1[2]=b[0]; p1[3]=b[1];
                p1[4]=c[0]; p1[5]=c[1]; p1[6]=d[0]; p1[7]=d[1];
            }
            half8_t* dst = (half8_t*)(xp + xp_off(dirbg, tb + i, w, lane));
            dst[0] = p0; dst[1] = p1;
        }

        // publish: __syncthreads drains vmcnt(0) for all threads' stores, then
        // agent-scope release (flushes this XCD's L2 to LLC) sets the flag.
        __syncthreads();
        if (tid == 0)
            __hip_atomic_store(flags + dirbg * 32 + chunk, MAGIC,
                               __ATOMIC_RELEASE, __HIP_MEMORY_SCOPE_AGENT);
        return;
    }

    // ================= CONSUMER: recurrence (r10 internals) ================
    const int wg  = blockIdx.x;        // dirbg 0..15
    const int dir = wg >> 3, bg = wg & 7;
    const float* Whh = dir ? Whh_b : Whh_f;
    const int fbase = wg * 32;

    _Float16 (*hsm)[16 * 136] = (_Float16 (*)[16 * 136])smem;   // 2 bufs

    half8_t awhh[4][4];
    #pragma unroll
    for (int T = 0; T < 4; ++T) {
        #pragma unroll
        for (int kk = 0; kk < 4; ++kk) {
            const float4* s = (const float4*)(Whh + (size_t)(T * 128 + w * 16 + lm) * 128 + kk * 32 + lq * 8);
            float4 v0 = s[0], v1 = s[1];
            half8_t h;
            half2_t a = pkrtz(v0.x, v0.y), b = pkrtz(v0.z, v0.w);
            half2_t c = pkrtz(v1.x, v1.y), d = pkrtz(v1.z, v1.w);
            h[0]=a[0]; h[1]=a[1]; h[2]=b[0]; h[3]=b[1];
            h[4]=c[0]; h[5]=c[1]; h[6]=d[0]; h[7]=d[1];
            awhh[T][kk] = h;
        }
    }

    for (int k = tid; k < 2 * 16 * 136; k += 512)
        ((_Float16*)hsm)[k] = (_Float16)0.0f;

    const _Float16* xp_wl = xp + ((size_t)wg * 512 * 8 + w) * 1024 + (size_t)lane * 16;

    // gate chunk(s) needed by the preload + first block
    {
        int c0 = dir ? 31 : 0;
        int c1 = dir ? 30 : 1;
        gate_chunks(flags, fbase, c0, c1, tid);
    }

    half8_t Qa[4], Qb[4];
    {
        int ta = dir ? (TT - 1) : 0;
        const half8_t* p = (const half8_t*)(xp_wl + (size_t)ta * 8192);
        Qa[0] = p[0]; Qb[0] = p[1];
    }
    {
        int ta = dir ? (TT - 2) : 1;
        const half8_t* p = (const half8_t*)(xp_wl + (size_t)ta * 8192);
        Qa[1] = p[0]; Qb[1] = p[1];
    }
    __syncthreads();

    half2_t c01 = h2(0.0f), c23 = h2(0.0f);
    half2_t hm01 = h2(-60000.0f), hm23 = h2(-60000.0f);

    for (int tbs = 0; tbs < TT; tbs += 4) {
        if ((tbs & 15) == 0) {
            int c = tbs >> 4;                       // 0..31
            int ccur = dir ? (31 - c) : c;
            int cnx  = dir ? (ccur - 1) : (ccur + 1);
            gate_chunks(flags, fbase, ccur, cnx, tid);
        }
        #pragma unroll
        for (int P = 0; P < 4; ++P) {
            const int t = tbs + P;
            {   // prefetch xp(t+2) into buffer (P+2)&3
                int tl = (t + 2 < TT) ? (t + 2) : (TT - 1);
                int ta = dir ? (TT - 1 - tl) : tl;
                const half8_t* pp = (const half8_t*)(xp_wl + (size_t)ta * 8192);
                Qa[(P + 2) & 3] = pp[0]; Qb[(P + 2) & 3] = pp[1];
            }

            half8_t bh[4];
            #pragma unroll
            for (int kk = 0; kk < 4; ++kk)
                bh[kk] = *(const half8_t*)&hsm[P & 1][lm * 136 + kk * 32 + lq * 8];

            float4_t acc[4];
            acc[0] = (float4_t){(float)Qa[P][0], (float)Qa[P][1], (float)Qa[P][2], (float)Qa[P][3]};
            acc[1] = (float4_t){(float)Qa[P][4], (float)Qa[P][5], (float)Qa[P][6], (float)Qa[P][7]};
            acc[2] = (float4_t){(float)Qb[P][0], (float)Qb[P][1], (float)Qb[P][2], (float)Qb[P][3]};
            acc[3] = (float4_t){(float)Qb[P][4], (float)Qb[P][5], (float)Qb[P][6], (float)Qb[P][7]};
            #pragma unroll
            for (int kk = 0; kk < 4; ++kk)
                #pragma unroll
                for (int T = 0; T < 4; ++T)
                    acc[T] = __builtin_amdgcn_mfma_f32_16x16x32_f16(awhh[T][kk], bh[kk], acc[T], 0, 0, 0);

            half2_t i01 = sigma_pk(pkrtz(acc[0][0], acc[0][1]));
            half2_t i23 = sigma_pk(pkrtz(acc[0][2], acc[0][3]));
            half2_t f01 = sigma_pk(pkrtz(acc[1][0], acc[1][1]));
            half2_t f23 = sigma_pk(pkrtz(acc[1][2], acc[1][3]));
            half2_t g01 = tanh_pk(pkrtz(acc[2][0], acc[2][1]));
            half2_t g23 = tanh_pk(pkrtz(acc[2][2], acc[2][3]));
            half2_t o01 = sigma_pk(pkrtz(acc[3][0], acc[3][1]));
            half2_t o23 = sigma_pk(pkrtz(acc[3][2], acc[3][3]));

            c01 = f01 * c01 + i01 * g01;
            c23 = f23 * c23 + i23 * g23;
            half2_t h01 = o01 * tanh_pk(c01);
            half2_t h23 = o23 * tanh_pk(c23);
            hm01 = __builtin_elementwise_max(hm01, h01);
            hm23 = __builtin_elementwise_max(hm23, h23);

            half4_t hv4;
            hv4[0] = h01[0]; hv4[1] = h01[1]; hv4[2] = h23[0]; hv4[3] = h23[1];
            *(half4_t*)&hsm[1 - (P & 1)][lm * 136 + w * 16 + lq * 4] = hv4;

            wg_barrier_lds();
        }
    }

    float4 o;
    o.x = (float)hm01[0]; o.y = (float)hm01[1];
    o.z = (float)hm23[0]; o.w = (float)hm23[1];
    *(float4*)&pooled[(size_t)(bg * 16 + lm) * 256 + dir * HH + w * 16 + lq * 4] = o;
}

// ---- kernel 2: pooled (128,256) -> relu(W1·+b1) -> sigmoid(W2·+b2) -> (128,1)
__global__ __launch_bounds__(64) void mlp_kernel(
    const float* __restrict__ pooled, const float* __restrict__ W1,
    const float* __restrict__ b1, const float* __restrict__ W2,
    const float* __restrict__ b2, float* __restrict__ out)
{
    const int b = blockIdx.x;
    const int j = threadIdx.x;
    const float4* p = (const float4*)(pooled + (size_t)b * 256);
    const float4* wv = (const float4*)(W1 + (size_t)j * 256);
    float s = 0.0f;
    #pragma unroll
    for (int q = 0; q < 64; ++q) {
        float4 pv = p[q];
        float4 ww = wv[q];
        s += pv.x * ww.x + pv.y * ww.y + pv.z * ww.z + pv.w * ww.w;
    }
    s += b1[j];
    s = fmaxf(s, 0.0f);
    float v = W2[j] * s;
    #pragma unroll
    for (int off = 32; off; off >>= 1) v += __shfl_down(v, off);
    if (j == 0) out[b] = 1.0f / (1.0f + __expf(-(v + b2[0])));
}

extern "C" void kernel_launch(void* const* d_in, const int* in_sizes, int n_in,
                              void* d_out, int out_size, void* d_ws, size_t ws_size,
                              hipStream_t stream) {
    const int*   x     = (const int*)d_in[0];
    const float* emb   = (const float*)d_in[1];
    const float* Wih_f = (const float*)d_in[2];
    const float* Whh_f = (const float*)d_in[3];
    const float* bih_f = (const float*)d_in[4];
    const float* bhh_f = (const float*)d_in[5];
    const float* Wih_b = (const float*)d_in[6];
    const float* Whh_b = (const float*)d_in[7];
    const float* bih_b = (const float*)d_in[8];
    const float* bhh_b = (const float*)d_in[9];
    const float* W1    = (const float*)d_in[10];
    const float* b1    = (const float*)d_in[11];
    const float* W2    = (const float*)d_in[12];
    const float* b2    = (const float*)d_in[13];
    float* out = (float*)d_out;

    char* ws = (char*)d_ws;
    float*    pooled = (float*)ws;                              // 128 KB
    _Float16* xp     = (_Float16*)(ws + 131072);                // 134.2 MB
    int*      flags  = (int*)(ws + 131072 + 134217728);         // 2 KB (poison != MAGIC)

    hipLaunchKernelGGL(bilstm_mega_kernel, dim3(528), dim3(512), 0, stream,
                       x, emb, Wih_f, bih_f, bhh_f, Wih_b, bih_b, bhh_b,
                       Whh_f, Whh_b, xp, flags, pooled);
    hipLaunchKernelGGL(mlp_kernel, dim3(128), dim3(64), 0, stream,
                       pooled, W1, b1, W2, b2, out);
}

// Round 13
// 502.395 us; speedup vs baseline: 1.0006x; 1.0006x over previous
//
#include <hip/hip_runtime.h>
#include <hip/hip_fp16.h>

#define TT 512
#define HH 128
#define MAGIC 0x13572468

typedef _Float16 half2_t __attribute__((ext_vector_type(2)));
typedef _Float16 half4_t __attribute__((ext_vector_type(4)));
typedef _Float16 half8_t __attribute__((ext_vector_type(8)));
typedef float    float4_t __attribute__((ext_vector_type(4)));

__device__ __forceinline__ half2_t h2(float v) {
    half2_t r; r[0] = (_Float16)v; r[1] = (_Float16)v; return r;
}
__device__ __forceinline__ half2_t pkrtz(float a, float b) {
    return __builtin_bit_cast(half2_t, __builtin_amdgcn_cvt_pkrtz(a, b));
}

// ---- packed-f16 polynomial activations (no transcendentals) ----
#define TC1 0.994940f
#define TC3 -0.290799f
#define TC5 0.065507f
#define TC7 -0.0062464f
#define SC1 0.2487350f
#define SC3 -0.0181749f
#define SC5 0.00102355f
#define SC7 -0.0000244141f

__device__ __forceinline__ half2_t tanh_pk(half2_t x) {
    half2_t m = __builtin_elementwise_min(__builtin_elementwise_max(x, h2(-2.0f)), h2(2.0f));
    half2_t t = m * m;
    half2_t p = h2(TC7) * t + h2(TC5);
    p = p * t + h2(TC3);
    p = p * t + h2(TC1);
    return m * p;
}
__device__ __forceinline__ half2_t sigma_pk(half2_t x) {
    half2_t m = __builtin_elementwise_min(__builtin_elementwise_max(x, h2(-4.0f)), h2(4.0f));
    half2_t t = m * m;
    half2_t p = h2(SC7) * t + h2(SC5);
    p = p * t + h2(SC3);
    p = p * t + h2(SC1);
    return m * p + h2(0.5f);
}

// LDS-only barrier: waits lgkmcnt(0), leaves global loads/stores in flight.
__device__ __forceinline__ void wg_barrier_lds() {
#if __has_builtin(__builtin_amdgcn_s_waitcnt)
    __builtin_amdgcn_s_waitcnt(0xC07F);   // lgkmcnt(0), vmcnt=max, expcnt=max
#else
    asm volatile("s_waitcnt lgkmcnt(0)" ::: "memory");
#endif
    __builtin_amdgcn_s_barrier();
}

// xp layout (f16): half index = (((dirbg*512 + t)*8 + w)*64 + lane)*16.
// Cache lines (128B) cover 4 lanes of ONE t -> lines never span chunk
// boundaries (critical for the producer/consumer coherence protocol).
__device__ __forceinline__ size_t xp_off(int dirbg, int t, int w, int lane) {
    return (((size_t)dirbg * 512 + t) * 8 + w) * 1024 + (size_t)lane * 16;
}

// consumer-side gate: tid0 acquire-spins, then block-wide barrier.
__device__ __forceinline__ void gate_chunks(const int* flags, int base, int c0, int c1, int tid) {
    if (tid == 0) {
        while (__hip_atomic_load(flags + base + c0, __ATOMIC_ACQUIRE,
                                 __HIP_MEMORY_SCOPE_AGENT) != MAGIC) {}
        if (c1 >= 0 && c1 < 32)
            while (__hip_atomic_load(flags + base + c1, __ATOMIC_ACQUIRE,
                                     __HIP_MEMORY_SCOPE_AGENT) != MAGIC) {}
    }
    __syncthreads();
}

// ---- mega kernel: WGs 0..15 = recurrence consumers (dirbg); WGs 16..527 =
// xp producers. Static LDS = 82 KB (> 160/2) so only ONE WG fits per CU:
// consumers get 16 exclusive CUs (no SIMD-sharing with producers — r12's
// 70.7 KB allowed 2 WGs/CU and producer waves halved consumer issue rate,
// +85us on the rec path). Producers: 512 WGs over the other 240 CUs.
__global__ __attribute__((amdgpu_flat_work_group_size(512, 512), amdgpu_waves_per_eu(2, 2)))
void bilstm_mega_kernel(
    const int* __restrict__ x, const float* __restrict__ emb,
    const float* __restrict__ Wih_f, const float* __restrict__ bih_f, const float* __restrict__ bhh_f,
    const float* __restrict__ Wih_b, const float* __restrict__ bih_b, const float* __restrict__ bhh_b,
    const float* __restrict__ Whh_f, const float* __restrict__ Whh_b,
    _Float16* __restrict__ xp, int* __restrict__ flags,
    float* __restrict__ pooled)
{
    __shared__ __align__(16) char smem[83968];   // 82 KB -> 1 WG/CU (exclusivity)

    const int tid = threadIdx.x;
    const int w = tid >> 6, lane = tid & 63, lq = lane >> 4, lm = lane & 15;

    if (blockIdx.x >= 16) {
        // ================= PRODUCER: staged xp GEMM for one chunk ==========
        const int pid  = blockIdx.x - 16;         // 0..511
        const int prio = pid >> 4;                // 0..31
        const int dirbg = pid & 15;
        const int dir = dirbg >> 3, bg = dirbg & 7;
        const int chunk = dir ? (31 - prio) : prio;
        const int tb = chunk * 16;

        const float* Wih = dir ? Wih_b : Wih_f;
        const float* bih = dir ? bih_b : bih_f;
        const float* bhh = dir ? bhh_b : bhh_f;

        int* id_sm = (int*)smem;                         // 256 ints
        _Float16* Esm = (_Float16*)(smem + 1024);        // [t*16+chain][136]

        if (tid < 256)
            id_sm[tid] = x[(size_t)(bg * 16 + (tid >> 4)) * TT + tb + (tid & 15)];

        half8_t awih[4][4];
        #pragma unroll
        for (int T = 0; T < 4; ++T) {
            #pragma unroll
            for (int kk = 0; kk < 4; ++kk) {
                const float4* s = (const float4*)(Wih + (size_t)(T * 128 + w * 16 + lm) * 128 + kk * 32 + lq * 8);
                float4 v0 = s[0], v1 = s[1];
                half8_t h;
                half2_t a = pkrtz(v0.x, v0.y), b = pkrtz(v0.z, v0.w);
                half2_t c = pkrtz(v1.x, v1.y), d = pkrtz(v1.z, v1.w);
                h[0]=a[0]; h[1]=a[1]; h[2]=b[0]; h[3]=b[1];
                h[4]=c[0]; h[5]=c[1]; h[6]=d[0]; h[7]=d[1];
                awih[T][kk] = h;
            }
        }
        float4_t biasv[4];
        #pragma unroll
        for (int T = 0; T < 4; ++T) {
            int g = T * 128 + w * 16 + lq * 4;
            float4 b1 = *(const float4*)(bih + g);
            float4 b2 = *(const float4*)(bhh + g);
            biasv[T] = (float4_t){b1.x + b2.x, b1.y + b2.y, b1.z + b2.z, b1.w + b2.w};
        }
        __syncthreads();   // id_sm ready

        {   // stage phase: 2 threads per (chain,t) row, 16 float4 each
            const int r  = tid >> 1;
            const int hf = tid & 1;
            const int chain = r >> 4, tt2 = r & 15;
            const float* src = emb + (size_t)id_sm[r] * 128 + hf * 64;
            float4 v[16];
            #pragma unroll
            for (int j = 0; j < 16; ++j) v[j] = *(const float4*)(src + 4 * j);
            _Float16* dst = &Esm[(tt2 * 16 + chain) * 136 + hf * 64];
            #pragma unroll
            for (int j = 0; j < 16; ++j) {
                half2_t a = pkrtz(v[j].x, v[j].y), b = pkrtz(v[j].z, v[j].w);
                half4_t q; q[0]=a[0]; q[1]=a[1]; q[2]=b[0]; q[3]=b[1];
                *(half4_t*)(dst + 4 * j) = q;
            }
        }
        __syncthreads();   // Esm ready

        #pragma unroll 4
        for (int i = 0; i < 16; ++i) {
            half8_t bfr[4];
            #pragma unroll
            for (int kk = 0; kk < 4; ++kk)
                bfr[kk] = *(const half8_t*)&Esm[(i * 16 + lm) * 136 + kk * 32 + lq * 8];

            float4_t acc[4];
            #pragma unroll
            for (int T = 0; T < 4; ++T) acc[T] = biasv[T];
            #pragma unroll
            for (int kk = 0; kk < 4; ++kk)
                #pragma unroll
                for (int T = 0; T < 4; ++T)
                    acc[T] = __builtin_amdgcn_mfma_f32_16x16x32_f16(awih[T][kk], bfr[kk], acc[T], 0, 0, 0);

            half8_t p0, p1;
            {
                half2_t a = pkrtz(acc[0][0], acc[0][1]), b = pkrtz(acc[0][2], acc[0][3]);
                half2_t c = pkrtz(acc[1][0], acc[1][1]), d = pkrtz(acc[1][2], acc[1][3]);
                p0[0]=a[0]; p0[1]=a[1]; p0[2]=b[0]; p0[3]=b[1];
                p0[4]=c[0]; p0[5]=c[1]; p0[6]=d[0]; p0[7]=d[1];
            }
            {
                half2_t a = pkrtz(acc[2][0], acc[2][1]), b = pkrtz(acc[2][2], acc[2][3]);
                half2_t c = pkrtz(acc[3][0], acc[3][1]), d = pkrtz(acc[3][2], acc[3][3]);
                p1[0]=a[0]; p1[1]=a[1]; p1[2]=b[0]; p1[3]=b[1];
                p1[4]=c[0]; p1[5]=c[1]; p1[6]=d[0]; p1[7]=d[1];
            }
            half8_t* dst = (half8_t*)(xp + xp_off(dirbg, tb + i, w, lane));
            dst[0] = p0; dst[1] = p1;
        }

        // publish: __syncthreads drains vmcnt(0), then agent-scope release.
        __syncthreads();
        if (tid == 0)
            __hip_atomic_store(flags + dirbg * 32 + chunk, MAGIC,
                               __ATOMIC_RELEASE, __HIP_MEMORY_SCOPE_AGENT);
        return;
    }

    // ================= CONSUMER: recurrence (r10 internals) ================
    const int wg  = blockIdx.x;        // dirbg 0..15
    const int dir = wg >> 3, bg = wg & 7;
    const float* Whh = dir ? Whh_b : Whh_f;
    const int fbase = wg * 32;

    _Float16 (*hsm)[16 * 136] = (_Float16 (*)[16 * 136])smem;   // 2 bufs

    half8_t awhh[4][4];
    #pragma unroll
    for (int T = 0; T < 4; ++T) {
        #pragma unroll
        for (int kk = 0; kk < 4; ++kk) {
            const float4* s = (const float4*)(Whh + (size_t)(T * 128 + w * 16 + lm) * 128 + kk * 32 + lq * 8);
            float4 v0 = s[0], v1 = s[1];
            half8_t h;
            half2_t a = pkrtz(v0.x, v0.y), b = pkrtz(v0.z, v0.w);
            half2_t c = pkrtz(v1.x, v1.y), d = pkrtz(v1.z, v1.w);
            h[0]=a[0]; h[1]=a[1]; h[2]=b[0]; h[3]=b[1];
            h[4]=c[0]; h[5]=c[1]; h[6]=d[0]; h[7]=d[1];
            awhh[T][kk] = h;
        }
    }

    for (int k = tid; k < 2 * 16 * 136; k += 512)
        ((_Float16*)hsm)[k] = (_Float16)0.0f;

    const _Float16* xp_wl = xp + ((size_t)wg * 512 * 8 + w) * 1024 + (size_t)lane * 16;

    // gate chunk(s) needed by the preload + first block
    {
        int c0 = dir ? 31 : 0;
        int c1 = dir ? 30 : 1;
        gate_chunks(flags, fbase, c0, c1, tid);
    }

    half8_t Qa[4], Qb[4];
    {
        int ta = dir ? (TT - 1) : 0;
        const half8_t* p = (const half8_t*)(xp_wl + (size_t)ta * 8192);
        Qa[0] = p[0]; Qb[0] = p[1];
    }
    {
        int ta = dir ? (TT - 2) : 1;
        const half8_t* p = (const half8_t*)(xp_wl + (size_t)ta * 8192);
        Qa[1] = p[0]; Qb[1] = p[1];
    }
    __syncthreads();

    half2_t c01 = h2(0.0f), c23 = h2(0.0f);
    half2_t hm01 = h2(-60000.0f), hm23 = h2(-60000.0f);

    for (int tbs = 0; tbs < TT; tbs += 4) {
        if ((tbs & 15) == 0) {
            int c = tbs >> 4;                       // 0..31
            int ccur = dir ? (31 - c) : c;
            int cnx  = dir ? (ccur - 1) : (ccur + 1);
            gate_chunks(flags, fbase, ccur, cnx, tid);
        }
        #pragma unroll
        for (int P = 0; P < 4; ++P) {
            const int t = tbs + P;
            {   // prefetch xp(t+2) into buffer (P+2)&3
                int tl = (t + 2 < TT) ? (t + 2) : (TT - 1);
                int ta = dir ? (TT - 1 - tl) : tl;
                const half8_t* pp = (const half8_t*)(xp_wl + (size_t)ta * 8192);
                Qa[(P + 2) & 3] = pp[0]; Qb[(P + 2) & 3] = pp[1];
            }

            half8_t bh[4];
            #pragma unroll
            for (int kk = 0; kk < 4; ++kk)
                bh[kk] = *(const half8_t*)&hsm[P & 1][lm * 136 + kk * 32 + lq * 8];

            float4_t acc[4];
            acc[0] = (float4_t){(float)Qa[P][0], (float)Qa[P][1], (float)Qa[P][2], (float)Qa[P][3]};
            acc[1] = (float4_t){(float)Qa[P][4], (float)Qa[P][5], (float)Qa[P][6], (float)Qa[P][7]};
            acc[2] = (float4_t){(float)Qb[P][0], (float)Qb[P][1], (float)Qb[P][2], (float)Qb[P][3]};
            acc[3] = (float4_t){(float)Qb[P][4], (float)Qb[P][5], (float)Qb[P][6], (float)Qb[P][7]};
            #pragma unroll
            for (int kk = 0; kk < 4; ++kk)
                #pragma unroll
                for (int T = 0; T < 4; ++T)
                    acc[T] = __builtin_amdgcn_mfma_f32_16x16x32_f16(awhh[T][kk], bh[kk], acc[T], 0, 0, 0);

            half2_t i01 = sigma_pk(pkrtz(acc[0][0], acc[0][1]));
            half2_t i23 = sigma_pk(pkrtz(acc[0][2], acc[0][3]));
            half2_t f01 = sigma_pk(pkrtz(acc[1][0], acc[1][1]));
            half2_t f23 = sigma_pk(pkrtz(acc[1][2], acc[1][3]));
            half2_t g01 = tanh_pk(pkrtz(acc[2][0], acc[2][1]));
            half2_t g23 = tanh_pk(pkrtz(acc[2][2], acc[2][3]));
            half2_t o01 = sigma_pk(pkrtz(acc[3][0], acc[3][1]));
            half2_t o23 = sigma_pk(pkrtz(acc[3][2], acc[3][3]));

            c01 = f01 * c01 + i01 * g01;
            c23 = f23 * c23 + i23 * g23;
            half2_t h01 = o01 * tanh_pk(c01);
            half2_t h23 = o23 * tanh_pk(c23);
            hm01 = __builtin_elementwise_max(hm01, h01);
            hm23 = __builtin_elementwise_max(hm23, h23);

            half4_t hv4;
            hv4[0] = h01[0]; hv4[1] = h01[1]; hv4[2] = h23[0]; hv4[3] = h23[1];
            *(half4_t*)&hsm[1 - (P & 1)][lm * 136 + w * 16 + lq * 4] = hv4;

            wg_barrier_lds();
        }
    }

    float4 o;
    o.x = (float)hm01[0]; o.y = (float)hm01[1];
    o.z = (float)hm23[0]; o.w = (float)hm23[1];
    *(float4*)&pooled[(size_t)(bg * 16 + lm) * 256 + dir * HH + w * 16 + lq * 4] = o;
}

// ---- kernel 2: pooled (128,256) -> relu(W1·+b1) -> sigmoid(W2·+b2) -> (128,1)
__global__ __launch_bounds__(64) void mlp_kernel(
    const float* __restrict__ pooled, const float* __restrict__ W1,
    const float* __restrict__ b1, const float* __restrict__ W2,
    const float* __restrict__ b2, float* __restrict__ out)
{
    const int b = blockIdx.x;
    const int j = threadIdx.x;
    const float4* p = (const float4*)(pooled + (size_t)b * 256);
    const float4* wv = (const float4*)(W1 + (size_t)j * 256);
    float s = 0.0f;
    #pragma unroll
    for (int q = 0; q < 64; ++q) {
        float4 pv = p[q];
        float4 ww = wv[q];
        s += pv.x * ww.x + pv.y * ww.y + pv.z * ww.z + pv.w * ww.w;
    }
    s += b1[j];
    s = fmaxf(s, 0.0f);
    float v = W2[j] * s;
    #pragma unroll
    for (int off = 32; off; off >>= 1) v += __shfl_down(v, off);
    if (j == 0) out[b] = 1.0f / (1.0f + __expf(-(v + b2[0])));
}

extern "C" void kernel_launch(void* const* d_in, const int* in_sizes, int n_in,
                              void* d_out, int out_size, void* d_ws, size_t ws_size,
                              hipStream_t stream) {
    const int*   x     = (const int*)d_in[0];
    const float* emb   = (const float*)d_in[1];
    const float* Wih_f = (const float*)d_in[2];
    const float* Whh_f = (const float*)d_in[3];
    const float* bih_f = (const float*)d_in[4];
    const float* bhh_f = (const float*)d_in[5];
    const float* Wih_b = (const float*)d_in[6];
    const float* Whh_b = (const float*)d_in[7];
    const float* bih_b = (const float*)d_in[8];
    const float* bhh_b = (const float*)d_in[9];
    const float* W1    = (const float*)d_in[10];
    const float* b1    = (const float*)d_in[11];
    const float* W2    = (const float*)d_in[12];
    const float* b2    = (const float*)d_in[13];
    float* out = (float*)d_out;

    char* ws = (char*)d_ws;
    float*    pooled = (float*)ws;                              // 128 KB
    _Float16* xp     = (_Float16*)(ws + 131072);                // 134.2 MB
    int*      flags  = (int*)(ws + 131072 + 134217728);         // 2 KB (poison != MAGIC)

    hipLaunchKernelGGL(bilstm_mega_kernel, dim3(528), dim3(512), 0, stream,
                       x, emb, Wih_f, bih_f, bhh_f, Wih_b, bih_b, bhh_b,
                       Whh_f, Whh_b, xp, flags, pooled);
    hipLaunchKernelGGL(mlp_kernel, dim3(128), dim3(64), 0, stream,
                       pooled, W1, b1, W2, b2, out);
}